// Round 9
// baseline (586.562 us; speedup 1.0000x reference)
//
#include <hip/hip_runtime.h>
#include <stdint.h>
#include <stddef.h>
#include <float.h>

typedef short bf16x8 __attribute__((ext_vector_type(8)));
typedef float f32x4 __attribute__((ext_vector_type(4)));

#define CAPG 210000  // per-group bucket capacity: mean 200K, +24 sigma

// ---------------- helpers ----------------
static __device__ __forceinline__ unsigned enc_min(float v) {
  unsigned u = __float_as_uint(v);
  return (u & 0x80000000u) ? ~u : (u | 0x80000000u);
}
static __device__ __forceinline__ unsigned short f2bf(float f) {
  unsigned u = __float_as_uint(f);
  u += 0x7fffu + ((u >> 16) & 1u);
  return (unsigned short)(u >> 16);
}
static __device__ __forceinline__ float bf2f(unsigned short b) {
  return __uint_as_float(((unsigned)b) << 16);
}
static __device__ __forceinline__ void acc8(float* a, uint4 v) {
  a[0] += __uint_as_float(v.x << 16);
  a[1] += __uint_as_float(v.x & 0xffff0000u);
  a[2] += __uint_as_float(v.y << 16);
  a[3] += __uint_as_float(v.y & 0xffff0000u);
  a[4] += __uint_as_float(v.z << 16);
  a[5] += __uint_as_float(v.z & 0xffff0000u);
  a[6] += __uint_as_float(v.w << 16);
  a[7] += __uint_as_float(v.w & 0xffff0000u);
}

// ---------------- edge partition: one pass, LDS-bucketed by dst group ----------------
// Reads the edge list ONCE (was: 8 full scans in k_count + 8 in k_fill).
// Bins (d,s) into 8 LDS buckets; flushes full buckets (>=256) to per-group
// global segments via one atomicAdd reservation + coalesced copies.
__global__ __launch_bounds__(256) void k_part(const int* __restrict__ edge, int E, int N,
                                              int* __restrict__ bkt_d, int* __restrict__ bkt_s,
                                              int* __restrict__ tails) {
  __shared__ unsigned long long lbuf[8][512];  // 32 KB
  __shared__ int lcnt[8];
  __shared__ int gb;
  int tid = threadIdx.x;
  if (tid < 8) lcnt[tid] = 0;
  __syncthreads();
  int stride = gridDim.x * 256;
  for (int base = blockIdx.x * 256; base < E; base += stride) {
    int e = base + tid;
    if (e < E) {
      unsigned s = (unsigned)edge[e];
      unsigned d = (unsigned)edge[E + e];
      int g = (int)(((unsigned long long)d * 8ull) / (unsigned)N);
      int pos = atomicAdd(&lcnt[g], 1);  // < 512 guaranteed by flush policy
      lbuf[g][pos] = ((unsigned long long)d << 32) | s;
    }
    __syncthreads();
    for (int g = 0; g < 8; ++g) {
      int c = lcnt[g];
      if (c >= 256) {  // flush so next round's <=256 adds cannot overflow
        if (tid == 0) gb = atomicAdd(&tails[g], c);
        __syncthreads();
        size_t seg = (size_t)g * CAPG + gb;
        for (int t = tid; t < c; t += 256) {
          unsigned long long p = lbuf[g][t];
          bkt_d[seg + t] = (int)(p >> 32);
          bkt_s[seg + t] = (int)(p & 0xffffffffu);
        }
        __syncthreads();
        if (tid == 0) lcnt[g] = 0;
        __syncthreads();
      }
    }
  }
  for (int g = 0; g < 8; ++g) {  // final flush
    int c = lcnt[g];
    if (c > 0) {
      if (tid == 0) gb = atomicAdd(&tails[g], c);
      __syncthreads();
      size_t seg = (size_t)g * CAPG + gb;
      for (int t = tid; t < c; t += 256) {
        unsigned long long p = lbuf[g][t];
        bkt_d[seg + t] = (int)(p >> 32);
        bkt_s[seg + t] = (int)(p & 0xffffffffu);
      }
      __syncthreads();
    }
  }
}

// ---------------- degree count from local bucket (XCD-resident atomics) ----------------
__global__ void k_count2(const int* __restrict__ bkt_d, const int* __restrict__ tails,
                         int* __restrict__ cnt) {
  int g = blockIdx.x & 7;
  int n = tails[g];
  const int* B = bkt_d + (size_t)g * CAPG;
  int start = (blockIdx.x >> 3) * blockDim.x + threadIdx.x;
  int step = (gridDim.x >> 3) * blockDim.x;
  for (int t = start; t < n; t += step) atomicAdd(&cnt[B[t]], 1);
}

// ---------------- block inclusive scan (1024/block) ----------------
__global__ void k_scan1(const int* __restrict__ cnt, int N,
                        int* __restrict__ incl, int* __restrict__ bsum) {
  __shared__ int sm[1024];
  int tid = threadIdx.x;
  int i = blockIdx.x * 1024 + tid;
  int v = (i < N) ? cnt[i] : 0;
  sm[tid] = v;
  __syncthreads();
  for (int off = 1; off < 1024; off <<= 1) {
    int t = (tid >= off) ? sm[tid - off] : 0;
    __syncthreads();
    sm[tid] += t;
    __syncthreads();
  }
  if (i < N) incl[i] = sm[tid];
  if (tid == 1023) bsum[blockIdx.x] = sm[1023];
}

// ---------------- scan of block sums (nb <= 128) ----------------
__global__ void k_scan2(const int* __restrict__ bsum, int nb, int* __restrict__ boff) {
  __shared__ int sm[128];
  int tid = threadIdx.x;
  int v = (tid < nb) ? bsum[tid] : 0;
  sm[tid] = v;
  __syncthreads();
  for (int off = 1; off < 128; off <<= 1) {
    int t = (tid >= off) ? sm[tid - off] : 0;
    __syncthreads();
    sm[tid] += t;
    __syncthreads();
  }
  if (tid < nb) boff[tid] = sm[tid] - v;  // exclusive
}

// ---------------- row_ptr / cursor / dinv ----------------
__global__ void k_aux(const int* __restrict__ cnt, const int* __restrict__ incl,
                      const int* __restrict__ boff, int N, int E,
                      int* __restrict__ row_ptr, int* __restrict__ cursor,
                      float* __restrict__ dinv) {
  int i = blockIdx.x * blockDim.x + threadIdx.x;
  if (i < N) {
    int rp = incl[i] - cnt[i] + boff[i >> 10];
    row_ptr[i] = rp;
    cursor[i] = rp;
    dinv[i] = 1.0f / sqrtf((float)(cnt[i] + 1));  // +1 self-loop
  } else if (i == N) {
    row_ptr[N] = E;
  }
}

// ---------------- CSR fill from local bucket (XCD-resident cursor + srcs) ------------
__global__ void k_fill2(const int* __restrict__ bkt_d, const int* __restrict__ bkt_s,
                        const int* __restrict__ tails,
                        int* __restrict__ cursor, int* __restrict__ srcs) {
  int g = blockIdx.x & 7;
  int n = tails[g];
  const int* Bd = bkt_d + (size_t)g * CAPG;
  const int* Bs = bkt_s + (size_t)g * CAPG;
  int start = (blockIdx.x >> 3) * blockDim.x + threadIdx.x;
  int step = (gridDim.x >> 3) * blockDim.x;
  for (int t = start; t < n; t += step) {
    int d = Bd[t];
    int s = Bs[t];
    int pos = atomicAdd(&cursor[d], 1);
    srcs[pos] = s;
  }
}

// ---------------- weight prep: W[k][n] fp32 -> lane-ordered bf16 hi/lo fragments -----
__global__ void k_prepw(const float* __restrict__ W1, const float* __restrict__ W2,
                        const float* __restrict__ W3,
                        unsigned short* __restrict__ w1h, unsigned short* __restrict__ w1l,
                        unsigned short* __restrict__ w2h, unsigned short* __restrict__ w2l,
                        unsigned short* __restrict__ w3h, unsigned short* __restrict__ w3l) {
  const int K = 128;
  int idx = blockIdx.x * 256 + threadIdx.x;
  const float* W;
  unsigned short *oh, *ol;
  int Nn, base;
  if (idx < 16384) { W = W1; Nn = 128; oh = w1h; ol = w1l; base = idx; }
  else if (idx < 32768) { W = W2; Nn = 128; oh = w2h; ol = w2l; base = idx - 16384; }
  else if (idx < 40960) { W = W3; Nn = 64; oh = w3h; ol = w3l; base = idx - 32768; }
  else return;
  int n = base / K, k = base % K;
  float w = W[(size_t)k * Nn + n];
  unsigned short h = f2bf(w);
  unsigned short l = f2bf(w - bf2f(h));
  int nf = n >> 4, mloc = n & 15, kci = k >> 5, quad = (k >> 3) & 3, j = k & 7;
  size_t o = ((size_t)((nf * 4 + kci) * 64 + quad * 16 + mloc)) * 8 + j;
  oh[o] = h;
  ol[o] = l;
}

// ---------------- MFMA GEMM: P = bf16((A @ W) * dinv[row]), 32ch-sliced layout -------
template <int NFW>
__global__ __launch_bounds__(256) void k_gemm_mfma(const float* __restrict__ A,
                                                   const unsigned short* __restrict__ Wfh,
                                                   const unsigned short* __restrict__ Wfl,
                                                   const float* __restrict__ dinv,
                                                   unsigned short* __restrict__ P, int M) {
  const int K = 128;
  __shared__ unsigned short Ah[64][136];
  __shared__ unsigned short Al[64][136];
  int tid = threadIdx.x;
  int m0 = blockIdx.x * 64;
  int w = tid >> 6, lane = tid & 63;

  bf16x8 bh[NFW][4], bl[NFW][4];
#pragma unroll
  for (int i = 0; i < NFW; ++i)
#pragma unroll
    for (int kci = 0; kci < 4; ++kci) {
      size_t o = ((size_t)(((w * NFW + i) * 4 + kci) * 64 + lane)) * 8;
      bh[i][kci] = *(const bf16x8*)&Wfh[o];
      bl[i][kci] = *(const bf16x8*)&Wfl[o];
    }

#pragma unroll
  for (int q = 0; q < 8; ++q) {
    int f = q * 256 + tid;
    int m = f >> 5, k4 = f & 31;
    int row = m0 + m;
    if (row >= M) row = M - 1;
    float4 v = *(const float4*)&A[(size_t)row * K + k4 * 4];
    unsigned short h0 = f2bf(v.x), h1 = f2bf(v.y), h2 = f2bf(v.z), h3 = f2bf(v.w);
    unsigned short l0 = f2bf(v.x - bf2f(h0)), l1 = f2bf(v.y - bf2f(h1));
    unsigned short l2 = f2bf(v.z - bf2f(h2)), l3 = f2bf(v.w - bf2f(h3));
    uint2 hh, ll;
    hh.x = (unsigned)h0 | ((unsigned)h1 << 16);
    hh.y = (unsigned)h2 | ((unsigned)h3 << 16);
    ll.x = (unsigned)l0 | ((unsigned)l1 << 16);
    ll.y = (unsigned)l2 | ((unsigned)l3 << 16);
    *(uint2*)&Ah[m][k4 * 4] = hh;
    *(uint2*)&Al[m][k4 * 4] = ll;
  }
  __syncthreads();

  int mloc = lane & 15, quad = lane >> 4;
  f32x4 acc[4][NFW];
#pragma unroll
  for (int rt = 0; rt < 4; ++rt)
#pragma unroll
    for (int i = 0; i < NFW; ++i) acc[rt][i] = (f32x4){0.f, 0.f, 0.f, 0.f};

#pragma unroll
  for (int rt = 0; rt < 4; ++rt) {
    const unsigned short* ph = &Ah[rt * 16 + mloc][quad * 8];
    const unsigned short* pl = &Al[rt * 16 + mloc][quad * 8];
#pragma unroll
    for (int kci = 0; kci < 4; ++kci) {
      bf16x8 ah = *(const bf16x8*)(ph + kci * 32);
      bf16x8 al = *(const bf16x8*)(pl + kci * 32);
#pragma unroll
      for (int i = 0; i < NFW; ++i) {
        acc[rt][i] = __builtin_amdgcn_mfma_f32_16x16x32_bf16(al, bh[i][kci], acc[rt][i], 0, 0, 0);
        acc[rt][i] = __builtin_amdgcn_mfma_f32_16x16x32_bf16(ah, bl[i][kci], acc[rt][i], 0, 0, 0);
        acc[rt][i] = __builtin_amdgcn_mfma_f32_16x16x32_bf16(ah, bh[i][kci], acc[rt][i], 0, 0, 0);
      }
    }
  }

#pragma unroll
  for (int rt = 0; rt < 4; ++rt) {
    int rbase = m0 + rt * 16 + quad * 4;
#pragma unroll
    for (int r = 0; r < 4; ++r) {
      int row = rbase + r;
      if (row < M) {
        float dv = dinv[row];
#pragma unroll
        for (int i = 0; i < NFW; ++i) {
          int nf = w * NFW + i;
          size_t o = (size_t)(nf >> 1) * M * 32 + (size_t)row * 32 + ((nf & 1) * 16 + mloc);
          P[o] = f2bf(acc[rt][i][r] * dv);
        }
      }
    }
  }
}

// ---------------- full-line sliced aggregation ----------------
template <int C, int RELU, int POOL>
__global__ __launch_bounds__(256) void k_agg4(const unsigned short* __restrict__ P,
                                              const int* __restrict__ row_ptr,
                                              const int* __restrict__ srcs,
                                              const float* __restrict__ dinv,
                                              const float* __restrict__ bias,
                                              float* __restrict__ Hout,
                                              unsigned* __restrict__ minenc, int N) {
  const int NS2 = C / 32;
  const int R = 8 / NS2;
  const int CAP = 448;
  __shared__ int s_idx[4][CAP];
  __shared__ float s_red[4][32];
  int tid = threadIdx.x;
  int wv = tid >> 6, lane = tid & 63;
  int b8 = blockIdx.x & 7;
  int slice = b8 / R, part = b8 % R;
  int g0 = ((blockIdx.x >> 3) * R + part) * 64 + wv * 16;
  const char* Pb = (const char*)P + (size_t)slice * N * 64;

  int i = lane >> 2, q = lane & 3;
  unsigned qoff = (unsigned)q * 16u;
  int d = g0 + i;
  int dc = d < N ? d : N - 1;
  bool valid = d < N;

  int e0 = row_ptr[g0 < N ? g0 : N];
  int e1 = row_ptr[(g0 + 16) < N ? (g0 + 16) : N];
  int lo_n = row_ptr[dc];
  int hi_n = row_ptr[valid ? d + 1 : dc];

  float a[8];
  {
    uint4 v = *(const uint4*)(Pb + ((unsigned)dc * 64u + qoff));
    a[0] = __uint_as_float(v.x << 16);
    a[1] = __uint_as_float(v.x & 0xffff0000u);
    a[2] = __uint_as_float(v.y << 16);
    a[3] = __uint_as_float(v.y & 0xffff0000u);
    a[4] = __uint_as_float(v.z << 16);
    a[5] = __uint_as_float(v.z & 0xffff0000u);
    a[6] = __uint_as_float(v.w << 16);
    a[7] = __uint_as_float(v.w & 0xffff0000u);
  }

  for (int w0 = e0; w0 < e1; w0 += CAP) {
    int wend = min(w0 + CAP, e1);
    int cnt = wend - w0;
    __builtin_amdgcn_wave_barrier();
    for (int t = lane; t < cnt; t += 64) s_idx[wv][t] = srcs[w0 + t];
    __builtin_amdgcn_wave_barrier();
    int j = max(lo_n, w0), hi = min(hi_n, wend);
    for (; j + 2 <= hi; j += 2) {
      unsigned i0 = (unsigned)s_idx[wv][j - w0];
      unsigned i1 = (unsigned)s_idx[wv][j - w0 + 1];
      uint4 v0 = *(const uint4*)(Pb + (i0 * 64u + qoff));
      uint4 v1 = *(const uint4*)(Pb + (i1 * 64u + qoff));
      acc8(a, v0);
      acc8(a, v1);
    }
    if (j < hi) {
      unsigned i0 = (unsigned)s_idx[wv][j - w0];
      uint4 v0 = *(const uint4*)(Pb + (i0 * 64u + qoff));
      acc8(a, v0);
    }
  }

  int c0 = slice * 32 + q * 8;
  float dv = dinv[dc];
  float4 bv0 = *(const float4*)&bias[c0];
  float4 bv1 = *(const float4*)&bias[c0 + 4];
  float h[8];
  h[0] = dv * a[0] + bv0.x; h[1] = dv * a[1] + bv0.y;
  h[2] = dv * a[2] + bv0.z; h[3] = dv * a[3] + bv0.w;
  h[4] = dv * a[4] + bv1.x; h[5] = dv * a[5] + bv1.y;
  h[6] = dv * a[6] + bv1.z; h[7] = dv * a[7] + bv1.w;
  if (RELU) {
#pragma unroll
    for (int k = 0; k < 8; ++k) h[k] = fmaxf(h[k], 0.f);
  }

  if (POOL) {
    if (!valid) {
#pragma unroll
      for (int k = 0; k < 8; ++k) h[k] = FLT_MAX;
    }
#pragma unroll
    for (int off = 4; off < 64; off <<= 1) {
#pragma unroll
      for (int k = 0; k < 8; ++k) h[k] = fminf(h[k], __shfl_xor(h[k], off, 64));
    }
    if (lane < 4) {
#pragma unroll
      for (int k = 0; k < 8; ++k) s_red[wv][q * 8 + k] = h[k];
    }
    __syncthreads();
    if (tid < 32) {
      float m = fminf(fminf(s_red[0][tid], s_red[1][tid]),
                      fminf(s_red[2][tid], s_red[3][tid]));
      atomicMin(&minenc[slice * 32 + tid], enc_min(m));
    }
  } else if (valid) {
    float4 o0 = make_float4(h[0], h[1], h[2], h[3]);
    float4 o1 = make_float4(h[4], h[5], h[6], h[7]);
    *(float4*)&Hout[(size_t)d * C + c0] = o0;
    *(float4*)&Hout[(size_t)d * C + c0 + 4] = o1;
  }
}

__global__ void k_decode(const unsigned* __restrict__ minenc, float* __restrict__ out) {
  int c = threadIdx.x;
  unsigned k = minenc[c];
  unsigned u = (k & 0x80000000u) ? (k & 0x7FFFFFFFu) : ~k;
  out[c] = __uint_as_float(u);
}

// ---------------- launch ----------------
extern "C" void kernel_launch(void* const* d_in, const int* in_sizes, int n_in,
                              void* d_out, int out_size, void* d_ws, size_t ws_size,
                              hipStream_t stream) {
  const float* X  = (const float*)d_in[0];
  const int* edge = (const int*)d_in[1];
  const float* W1 = (const float*)d_in[2];
  const float* b1 = (const float*)d_in[3];
  const float* W2 = (const float*)d_in[4];
  const float* b2 = (const float*)d_in[5];
  const float* W3 = (const float*)d_in[6];
  const float* b3 = (const float*)d_in[7];
  float* out = (float*)d_out;

  const int IN_CH = 128;
  int N = in_sizes[0] / IN_CH;
  int E = in_sizes[1] / 2;

  char* ws = (char*)d_ws;
  size_t off = 0;
  auto alloc = [&](size_t bytes) {
    void* p = ws + off;
    off = (off + bytes + 255) & ~(size_t)255;
    return p;
  };
  unsigned short* P = (unsigned short*)alloc((size_t)N * 128 * 2);  // 25.6 MB bf16, sliced
  float* H       = (float*)alloc((size_t)N * 128 * 4);              // 51.2 MB
  int* srcs      = (int*)alloc((size_t)E * 4);                      // 6.4 MB
  int* bkt_d     = (int*)alloc((size_t)8 * CAPG * 4);               // 6.72 MB
  int* bkt_s     = (int*)alloc((size_t)8 * CAPG * 4);               // 6.72 MB
  int* cnt       = (int*)alloc((size_t)N * 4);
  int* incl      = (int*)alloc((size_t)N * 4);
  int* row_ptr   = (int*)alloc((size_t)(N + 1) * 4);
  int* cursor    = (int*)alloc((size_t)N * 4);
  float* dinv    = (float*)alloc((size_t)N * 4);
  int* bsum      = (int*)alloc(1024);
  int* boff      = (int*)alloc(1024);
  int* tails     = (int*)alloc(256);
  unsigned* minenc = (unsigned*)alloc(256);
  unsigned short* w1h = (unsigned short*)alloc(16384 * 2);
  unsigned short* w1l = (unsigned short*)alloc(16384 * 2);
  unsigned short* w2h = (unsigned short*)alloc(16384 * 2);
  unsigned short* w2l = (unsigned short*)alloc(16384 * 2);
  unsigned short* w3h = (unsigned short*)alloc(8192 * 2);
  unsigned short* w3l = (unsigned short*)alloc(8192 * 2);

  hipMemsetAsync(cnt, 0, (size_t)N * 4, stream);
  hipMemsetAsync(tails, 0, 32, stream);
  hipMemsetAsync(minenc, 0xFF, 64 * 4, stream);  // encoded +max

  int nb = (N + 1023) / 1024;
  k_prepw<<<160, 256, 0, stream>>>(W1, W2, W3, w1h, w1l, w2h, w2l, w3h, w3l);
  k_part<<<1024, 256, 0, stream>>>(edge, E, N, bkt_d, bkt_s, tails);
  k_count2<<<1024, 256, 0, stream>>>(bkt_d, tails, cnt);
  k_scan1<<<nb, 1024, 0, stream>>>(cnt, N, incl, bsum);
  k_scan2<<<1, 128, 0, stream>>>(bsum, nb, boff);
  k_aux<<<(N + 256) / 256, 256, 0, stream>>>(cnt, incl, boff, N, E, row_ptr, cursor, dinv);
  k_fill2<<<1024, 256, 0, stream>>>(bkt_d, bkt_s, tails, cursor, srcs);

  int gx = (N + 63) / 64;
  int c128 = (N + 127) / 128;  // chunks for C=128 (R=2 parts x 64 nodes)
  int c64  = (N + 255) / 256;  // chunks for C=64  (R=4 parts x 64 nodes)
  // layer 1
  k_gemm_mfma<2><<<gx, 256, 0, stream>>>(X, w1h, w1l, dinv, P, N);
  k_agg4<128, 1, 0><<<c128 * 8, 256, 0, stream>>>(P, row_ptr, srcs, dinv, b1, H, minenc, N);
  // layer 2
  k_gemm_mfma<2><<<gx, 256, 0, stream>>>(H, w2h, w2l, dinv, P, N);
  k_agg4<128, 1, 0><<<c128 * 8, 256, 0, stream>>>(P, row_ptr, srcs, dinv, b2, H, minenc, N);
  // layer 3 (64 ch, no relu) with fused min-pool
  k_gemm_mfma<1><<<gx, 256, 0, stream>>>(H, w3h, w3l, dinv, P, N);
  k_agg4<64, 0, 1><<<c64 * 8, 256, 0, stream>>>(P, row_ptr, srcs, dinv, b3, nullptr, minenc, N);
  // decode encoded mins -> out[64]
  k_decode<<<1, 64, 0, stream>>>(minenc, out);
}

// Round 10
// 490.052 us; speedup vs baseline: 1.1969x; 1.1969x over previous
//
#include <hip/hip_runtime.h>
#include <stdint.h>
#include <stddef.h>
#include <float.h>

typedef short bf16x8 __attribute__((ext_vector_type(8)));
typedef float f32x4 __attribute__((ext_vector_type(4)));

// ---------------- helpers ----------------
static __device__ __forceinline__ unsigned enc_min(float v) {
  unsigned u = __float_as_uint(v);
  return (u & 0x80000000u) ? ~u : (u | 0x80000000u);
}
static __device__ __forceinline__ unsigned short f2bf(float f) {
  unsigned u = __float_as_uint(f);
  u += 0x7fffu + ((u >> 16) & 1u);
  return (unsigned short)(u >> 16);
}
static __device__ __forceinline__ float bf2f(unsigned short b) {
  return __uint_as_float(((unsigned)b) << 16);
}
static __device__ __forceinline__ void acc8(float* a, uint4 v) {
  a[0] += __uint_as_float(v.x << 16);
  a[1] += __uint_as_float(v.x & 0xffff0000u);
  a[2] += __uint_as_float(v.y << 16);
  a[3] += __uint_as_float(v.y & 0xffff0000u);
  a[4] += __uint_as_float(v.z << 16);
  a[5] += __uint_as_float(v.z & 0xffff0000u);
  a[6] += __uint_as_float(v.w << 16);
  a[7] += __uint_as_float(v.w & 0xffff0000u);
}

// ---------------- degree count, XCD-binned, nt edge stream ----------------
// blockIdx%8 -> XCD heuristic keeps each cnt slice in ONE XCD's L2.
// Edge reads are non-temporal: zero-reuse stream must not evict the
// scattered cnt lines (R8: L2 thrash caused partial-line writebacks).
__global__ void k_count(const int* __restrict__ edge, int E, int N, int* __restrict__ cnt) {
  int grp = blockIdx.x & 7;
  int bslot = blockIdx.x >> 3;
  int nslot = gridDim.x >> 3;
  int lo = (int)(((long long)N * grp) >> 3);
  int hi = (int)(((long long)N * (grp + 1)) >> 3);
  for (int e = bslot * blockDim.x + threadIdx.x; e < E; e += nslot * blockDim.x) {
    int d = __builtin_nontemporal_load(&edge[E + e]);
    if (d >= lo && d < hi) atomicAdd(&cnt[d], 1);
  }
}

// ---------------- block inclusive scan (1024/block) ----------------
__global__ void k_scan1(const int* __restrict__ cnt, int N,
                        int* __restrict__ incl, int* __restrict__ bsum) {
  __shared__ int sm[1024];
  int tid = threadIdx.x;
  int i = blockIdx.x * 1024 + tid;
  int v = (i < N) ? cnt[i] : 0;
  sm[tid] = v;
  __syncthreads();
  for (int off = 1; off < 1024; off <<= 1) {
    int t = (tid >= off) ? sm[tid - off] : 0;
    __syncthreads();
    sm[tid] += t;
    __syncthreads();
  }
  if (i < N) incl[i] = sm[tid];
  if (tid == 1023) bsum[blockIdx.x] = sm[1023];
}

// ---------------- scan of block sums (nb <= 128) ----------------
__global__ void k_scan2(const int* __restrict__ bsum, int nb, int* __restrict__ boff) {
  __shared__ int sm[128];
  int tid = threadIdx.x;
  int v = (tid < nb) ? bsum[tid] : 0;
  sm[tid] = v;
  __syncthreads();
  for (int off = 1; off < 128; off <<= 1) {
    int t = (tid >= off) ? sm[tid - off] : 0;
    __syncthreads();
    sm[tid] += t;
    __syncthreads();
  }
  if (tid < nb) boff[tid] = sm[tid] - v;  // exclusive
}

// ---------------- row_ptr / cursor / dinv ----------------
__global__ void k_aux(const int* __restrict__ cnt, const int* __restrict__ incl,
                      const int* __restrict__ boff, int N, int E,
                      int* __restrict__ row_ptr, int* __restrict__ cursor,
                      float* __restrict__ dinv) {
  int i = blockIdx.x * blockDim.x + threadIdx.x;
  if (i < N) {
    int rp = incl[i] - cnt[i] + boff[i >> 10];
    row_ptr[i] = rp;
    cursor[i] = rp;
    dinv[i] = 1.0f / sqrtf((float)(cnt[i] + 1));  // +1 self-loop
  } else if (i == N) {
    row_ptr[N] = E;
  }
}

// ---------------- CSR fill (bucket by dst, store src), XCD-binned, nt stream --------
__global__ void k_fill(const int* __restrict__ edge, int E, int N,
                       int* __restrict__ cursor, int* __restrict__ srcs) {
  int grp = blockIdx.x & 7;
  int bslot = blockIdx.x >> 3;
  int nslot = gridDim.x >> 3;
  int lo = (int)(((long long)N * grp) >> 3);
  int hi = (int)(((long long)N * (grp + 1)) >> 3);
  for (int e = bslot * blockDim.x + threadIdx.x; e < E; e += nslot * blockDim.x) {
    int d = __builtin_nontemporal_load(&edge[E + e]);
    if (d >= lo && d < hi) {
      int s = __builtin_nontemporal_load(&edge[e]);
      int pos = atomicAdd(&cursor[d], 1);
      srcs[pos] = s;  // cached store: lines fill in this XCD's L2
    }
  }
}

// ---------------- weight prep: W[k][n] fp32 -> lane-ordered bf16 hi/lo fragments -----
__global__ void k_prepw(const float* __restrict__ W1, const float* __restrict__ W2,
                        const float* __restrict__ W3,
                        unsigned short* __restrict__ w1h, unsigned short* __restrict__ w1l,
                        unsigned short* __restrict__ w2h, unsigned short* __restrict__ w2l,
                        unsigned short* __restrict__ w3h, unsigned short* __restrict__ w3l) {
  const int K = 128;
  int idx = blockIdx.x * 256 + threadIdx.x;
  const float* W;
  unsigned short *oh, *ol;
  int Nn, base;
  if (idx < 16384) { W = W1; Nn = 128; oh = w1h; ol = w1l; base = idx; }
  else if (idx < 32768) { W = W2; Nn = 128; oh = w2h; ol = w2l; base = idx - 16384; }
  else if (idx < 40960) { W = W3; Nn = 64; oh = w3h; ol = w3l; base = idx - 32768; }
  else return;
  int n = base / K, k = base % K;
  float w = W[(size_t)k * Nn + n];
  unsigned short h = f2bf(w);
  unsigned short l = f2bf(w - bf2f(h));
  int nf = n >> 4, mloc = n & 15, kci = k >> 5, quad = (k >> 3) & 3, j = k & 7;
  size_t o = ((size_t)((nf * 4 + kci) * 64 + quad * 16 + mloc)) * 8 + j;
  oh[o] = h;
  ol[o] = l;
}

// ---------------- MFMA GEMM: P = bf16((A @ W) * dinv[row]), 32ch-sliced layout -------
template <int NFW>
__global__ __launch_bounds__(256) void k_gemm_mfma(const float* __restrict__ A,
                                                   const unsigned short* __restrict__ Wfh,
                                                   const unsigned short* __restrict__ Wfl,
                                                   const float* __restrict__ dinv,
                                                   unsigned short* __restrict__ P, int M) {
  const int K = 128;
  __shared__ unsigned short Ah[64][136];
  __shared__ unsigned short Al[64][136];
  int tid = threadIdx.x;
  int m0 = blockIdx.x * 64;
  int w = tid >> 6, lane = tid & 63;

  bf16x8 bh[NFW][4], bl[NFW][4];
#pragma unroll
  for (int i = 0; i < NFW; ++i)
#pragma unroll
    for (int kci = 0; kci < 4; ++kci) {
      size_t o = ((size_t)(((w * NFW + i) * 4 + kci) * 64 + lane)) * 8;
      bh[i][kci] = *(const bf16x8*)&Wfh[o];
      bl[i][kci] = *(const bf16x8*)&Wfl[o];
    }

#pragma unroll
  for (int q = 0; q < 8; ++q) {
    int f = q * 256 + tid;
    int m = f >> 5, k4 = f & 31;
    int row = m0 + m;
    if (row >= M) row = M - 1;
    float4 v = *(const float4*)&A[(size_t)row * K + k4 * 4];
    unsigned short h0 = f2bf(v.x), h1 = f2bf(v.y), h2 = f2bf(v.z), h3 = f2bf(v.w);
    unsigned short l0 = f2bf(v.x - bf2f(h0)), l1 = f2bf(v.y - bf2f(h1));
    unsigned short l2 = f2bf(v.z - bf2f(h2)), l3 = f2bf(v.w - bf2f(h3));
    uint2 hh, ll;
    hh.x = (unsigned)h0 | ((unsigned)h1 << 16);
    hh.y = (unsigned)h2 | ((unsigned)h3 << 16);
    ll.x = (unsigned)l0 | ((unsigned)l1 << 16);
    ll.y = (unsigned)l2 | ((unsigned)l3 << 16);
    *(uint2*)&Ah[m][k4 * 4] = hh;
    *(uint2*)&Al[m][k4 * 4] = ll;
  }
  __syncthreads();

  int mloc = lane & 15, quad = lane >> 4;
  f32x4 acc[4][NFW];
#pragma unroll
  for (int rt = 0; rt < 4; ++rt)
#pragma unroll
    for (int i = 0; i < NFW; ++i) acc[rt][i] = (f32x4){0.f, 0.f, 0.f, 0.f};

#pragma unroll
  for (int rt = 0; rt < 4; ++rt) {
    const unsigned short* ph = &Ah[rt * 16 + mloc][quad * 8];
    const unsigned short* pl = &Al[rt * 16 + mloc][quad * 8];
#pragma unroll
    for (int kci = 0; kci < 4; ++kci) {
      bf16x8 ah = *(const bf16x8*)(ph + kci * 32);
      bf16x8 al = *(const bf16x8*)(pl + kci * 32);
#pragma unroll
      for (int i = 0; i < NFW; ++i) {
        acc[rt][i] = __builtin_amdgcn_mfma_f32_16x16x32_bf16(al, bh[i][kci], acc[rt][i], 0, 0, 0);
        acc[rt][i] = __builtin_amdgcn_mfma_f32_16x16x32_bf16(ah, bl[i][kci], acc[rt][i], 0, 0, 0);
        acc[rt][i] = __builtin_amdgcn_mfma_f32_16x16x32_bf16(ah, bh[i][kci], acc[rt][i], 0, 0, 0);
      }
    }
  }

#pragma unroll
  for (int rt = 0; rt < 4; ++rt) {
    int rbase = m0 + rt * 16 + quad * 4;
#pragma unroll
    for (int r = 0; r < 4; ++r) {
      int row = rbase + r;
      if (row < M) {
        float dv = dinv[row];
#pragma unroll
        for (int i = 0; i < NFW; ++i) {
          int nf = w * NFW + i;
          size_t o = (size_t)(nf >> 1) * M * 32 + (size_t)row * 32 + ((nf & 1) * 16 + mloc);
          P[o] = f2bf(acc[rt][i][r] * dv);
        }
      }
    }
  }
}

// ---------------- full-line sliced aggregation ----------------
// Slice = 32 ch = 64-B node row -> one edge-gather = one fully-used line.
// Slice served by an XCD pair (C=128) / quad (C=64) via blockIdx%8.
template <int C, int RELU, int POOL>
__global__ __launch_bounds__(256) void k_agg4(const unsigned short* __restrict__ P,
                                              const int* __restrict__ row_ptr,
                                              const int* __restrict__ srcs,
                                              const float* __restrict__ dinv,
                                              const float* __restrict__ bias,
                                              float* __restrict__ Hout,
                                              unsigned* __restrict__ minenc, int N) {
  const int NS2 = C / 32;
  const int R = 8 / NS2;
  const int CAP = 448;
  __shared__ int s_idx[4][CAP];
  __shared__ float s_red[4][32];
  int tid = threadIdx.x;
  int wv = tid >> 6, lane = tid & 63;
  int b8 = blockIdx.x & 7;
  int slice = b8 / R, part = b8 % R;
  int g0 = ((blockIdx.x >> 3) * R + part) * 64 + wv * 16;
  const char* Pb = (const char*)P + (size_t)slice * N * 64;

  int i = lane >> 2, q = lane & 3;
  unsigned qoff = (unsigned)q * 16u;
  int d = g0 + i;
  int dc = d < N ? d : N - 1;
  bool valid = d < N;

  int e0 = row_ptr[g0 < N ? g0 : N];
  int e1 = row_ptr[(g0 + 16) < N ? (g0 + 16) : N];
  int lo_n = row_ptr[dc];
  int hi_n = row_ptr[valid ? d + 1 : dc];

  float a[8];
  {
    uint4 v = *(const uint4*)(Pb + ((unsigned)dc * 64u + qoff));
    a[0] = __uint_as_float(v.x << 16);
    a[1] = __uint_as_float(v.x & 0xffff0000u);
    a[2] = __uint_as_float(v.y << 16);
    a[3] = __uint_as_float(v.y & 0xffff0000u);
    a[4] = __uint_as_float(v.z << 16);
    a[5] = __uint_as_float(v.z & 0xffff0000u);
    a[6] = __uint_as_float(v.w << 16);
    a[7] = __uint_as_float(v.w & 0xffff0000u);
  }

  for (int w0 = e0; w0 < e1; w0 += CAP) {
    int wend = min(w0 + CAP, e1);
    int cnt = wend - w0;
    __builtin_amdgcn_wave_barrier();
    for (int t = lane; t < cnt; t += 64) s_idx[wv][t] = srcs[w0 + t];
    __builtin_amdgcn_wave_barrier();
    int j = max(lo_n, w0), hi = min(hi_n, wend);
    for (; j + 2 <= hi; j += 2) {
      unsigned i0 = (unsigned)s_idx[wv][j - w0];
      unsigned i1 = (unsigned)s_idx[wv][j - w0 + 1];
      uint4 v0 = *(const uint4*)(Pb + (i0 * 64u + qoff));
      uint4 v1 = *(const uint4*)(Pb + (i1 * 64u + qoff));
      acc8(a, v0);
      acc8(a, v1);
    }
    if (j < hi) {
      unsigned i0 = (unsigned)s_idx[wv][j - w0];
      uint4 v0 = *(const uint4*)(Pb + (i0 * 64u + qoff));
      acc8(a, v0);
    }
  }

  int c0 = slice * 32 + q * 8;
  float dv = dinv[dc];
  float4 bv0 = *(const float4*)&bias[c0];
  float4 bv1 = *(const float4*)&bias[c0 + 4];
  float h[8];
  h[0] = dv * a[0] + bv0.x; h[1] = dv * a[1] + bv0.y;
  h[2] = dv * a[2] + bv0.z; h[3] = dv * a[3] + bv0.w;
  h[4] = dv * a[4] + bv1.x; h[5] = dv * a[5] + bv1.y;
  h[6] = dv * a[6] + bv1.z; h[7] = dv * a[7] + bv1.w;
  if (RELU) {
#pragma unroll
    for (int k = 0; k < 8; ++k) h[k] = fmaxf(h[k], 0.f);
  }

  if (POOL) {
    if (!valid) {
#pragma unroll
      for (int k = 0; k < 8; ++k) h[k] = FLT_MAX;
    }
#pragma unroll
    for (int off = 4; off < 64; off <<= 1) {
#pragma unroll
      for (int k = 0; k < 8; ++k) h[k] = fminf(h[k], __shfl_xor(h[k], off, 64));
    }
    if (lane < 4) {
#pragma unroll
      for (int k = 0; k < 8; ++k) s_red[wv][q * 8 + k] = h[k];
    }
    __syncthreads();
    if (tid < 32) {
      float m = fminf(fminf(s_red[0][tid], s_red[1][tid]),
                      fminf(s_red[2][tid], s_red[3][tid]));
      atomicMin(&minenc[slice * 32 + tid], enc_min(m));
    }
  } else if (valid) {
    float4 o0 = make_float4(h[0], h[1], h[2], h[3]);
    float4 o1 = make_float4(h[4], h[5], h[6], h[7]);
    *(float4*)&Hout[(size_t)d * C + c0] = o0;
    *(float4*)&Hout[(size_t)d * C + c0 + 4] = o1;
  }
}

__global__ void k_decode(const unsigned* __restrict__ minenc, float* __restrict__ out) {
  int c = threadIdx.x;
  unsigned k = minenc[c];
  unsigned u = (k & 0x80000000u) ? (k & 0x7FFFFFFFu) : ~k;
  out[c] = __uint_as_float(u);
}

// ---------------- launch ----------------
extern "C" void kernel_launch(void* const* d_in, const int* in_sizes, int n_in,
                              void* d_out, int out_size, void* d_ws, size_t ws_size,
                              hipStream_t stream) {
  const float* X  = (const float*)d_in[0];
  const int* edge = (const int*)d_in[1];
  const float* W1 = (const float*)d_in[2];
  const float* b1 = (const float*)d_in[3];
  const float* W2 = (const float*)d_in[4];
  const float* b2 = (const float*)d_in[5];
  const float* W3 = (const float*)d_in[6];
  const float* b3 = (const float*)d_in[7];
  float* out = (float*)d_out;

  const int IN_CH = 128;
  int N = in_sizes[0] / IN_CH;
  int E = in_sizes[1] / 2;

  char* ws = (char*)d_ws;
  size_t off = 0;
  auto alloc = [&](size_t bytes) {
    void* p = ws + off;
    off = (off + bytes + 255) & ~(size_t)255;
    return p;
  };
  unsigned short* P = (unsigned short*)alloc((size_t)N * 128 * 2);  // 25.6 MB bf16, sliced
  float* H       = (float*)alloc((size_t)N * 128 * 4);              // 51.2 MB
  int* srcs      = (int*)alloc((size_t)E * 4);                      // 6.4 MB
  int* cnt       = (int*)alloc((size_t)N * 4);
  int* incl      = (int*)alloc((size_t)N * 4);
  int* row_ptr   = (int*)alloc((size_t)(N + 1) * 4);
  int* cursor    = (int*)alloc((size_t)N * 4);
  float* dinv    = (float*)alloc((size_t)N * 4);
  int* bsum      = (int*)alloc(1024);
  int* boff      = (int*)alloc(1024);
  unsigned* minenc = (unsigned*)alloc(256);
  unsigned short* w1h = (unsigned short*)alloc(16384 * 2);
  unsigned short* w1l = (unsigned short*)alloc(16384 * 2);
  unsigned short* w2h = (unsigned short*)alloc(16384 * 2);
  unsigned short* w2l = (unsigned short*)alloc(16384 * 2);
  unsigned short* w3h = (unsigned short*)alloc(8192 * 2);
  unsigned short* w3l = (unsigned short*)alloc(8192 * 2);

  hipMemsetAsync(cnt, 0, (size_t)N * 4, stream);
  hipMemsetAsync(minenc, 0xFF, 64 * 4, stream);  // encoded +max

  int nb = (N + 1023) / 1024;
  k_prepw<<<160, 256, 0, stream>>>(W1, W2, W3, w1h, w1l, w2h, w2l, w3h, w3l);
  k_count<<<1024, 256, 0, stream>>>(edge, E, N, cnt);
  k_scan1<<<nb, 1024, 0, stream>>>(cnt, N, incl, bsum);
  k_scan2<<<1, 128, 0, stream>>>(bsum, nb, boff);
  k_aux<<<(N + 256) / 256, 256, 0, stream>>>(cnt, incl, boff, N, E, row_ptr, cursor, dinv);
  k_fill<<<1024, 256, 0, stream>>>(edge, E, N, cursor, srcs);

  int gx = (N + 63) / 64;
  int c128 = (N + 127) / 128;  // chunks for C=128 (R=2 parts x 64 nodes)
  int c64  = (N + 255) / 256;  // chunks for C=64  (R=4 parts x 64 nodes)
  // layer 1
  k_gemm_mfma<2><<<gx, 256, 0, stream>>>(X, w1h, w1l, dinv, P, N);
  k_agg4<128, 1, 0><<<c128 * 8, 256, 0, stream>>>(P, row_ptr, srcs, dinv, b1, H, minenc, N);
  // layer 2
  k_gemm_mfma<2><<<gx, 256, 0, stream>>>(H, w2h, w2l, dinv, P, N);
  k_agg4<128, 1, 0><<<c128 * 8, 256, 0, stream>>>(P, row_ptr, srcs, dinv, b2, H, minenc, N);
  // layer 3 (64 ch, no relu) with fused min-pool
  k_gemm_mfma<1><<<gx, 256, 0, stream>>>(H, w3h, w3l, dinv, P, N);
  k_agg4<64, 0, 1><<<c64 * 8, 256, 0, stream>>>(P, row_ptr, srcs, dinv, b3, nullptr, minenc, N);
  // decode encoded mins -> out[64]
  k_decode<<<1, 64, 0, stream>>>(minenc, out);
}

// Round 11
// 480.692 us; speedup vs baseline: 1.2202x; 1.0195x over previous
//
#include <hip/hip_runtime.h>
#include <stdint.h>
#include <stddef.h>
#include <float.h>

typedef short bf16x8 __attribute__((ext_vector_type(8)));
typedef float f32x4 __attribute__((ext_vector_type(4)));

// ---------------- helpers ----------------
static __device__ __forceinline__ unsigned enc_min(float v) {
  unsigned u = __float_as_uint(v);
  return (u & 0x80000000u) ? ~u : (u | 0x80000000u);
}
static __device__ __forceinline__ unsigned short f2bf(float f) {
  unsigned u = __float_as_uint(f);
  u += 0x7fffu + ((u >> 16) & 1u);
  return (unsigned short)(u >> 16);
}
static __device__ __forceinline__ float bf2f(unsigned short b) {
  return __uint_as_float(((unsigned)b) << 16);
}
static __device__ __forceinline__ void acc8(float* a, uint4 v) {
  a[0] += __uint_as_float(v.x << 16);
  a[1] += __uint_as_float(v.x & 0xffff0000u);
  a[2] += __uint_as_float(v.y << 16);
  a[3] += __uint_as_float(v.y & 0xffff0000u);
  a[4] += __uint_as_float(v.z << 16);
  a[5] += __uint_as_float(v.z & 0xffff0000u);
  a[6] += __uint_as_float(v.w << 16);
  a[7] += __uint_as_float(v.w & 0xffff0000u);
}

// ---------------- degree count, XCD-binned ----------------
__global__ void k_count(const int* __restrict__ edge, int E, int N, int* __restrict__ cnt) {
  int grp = blockIdx.x & 7;
  int bslot = blockIdx.x >> 3;
  int nslot = gridDim.x >> 3;
  int lo = (int)(((long long)N * grp) >> 3);
  int hi = (int)(((long long)N * (grp + 1)) >> 3);
  for (int e = bslot * blockDim.x + threadIdx.x; e < E; e += nslot * blockDim.x) {
    int d = edge[E + e];
    if (d >= lo && d < hi) atomicAdd(&cnt[d], 1);
  }
}

// ---------------- block inclusive scan (1024/block) ----------------
__global__ void k_scan1(const int* __restrict__ cnt, int N,
                        int* __restrict__ incl, int* __restrict__ bsum) {
  __shared__ int sm[1024];
  int tid = threadIdx.x;
  int i = blockIdx.x * 1024 + tid;
  int v = (i < N) ? cnt[i] : 0;
  sm[tid] = v;
  __syncthreads();
  for (int off = 1; off < 1024; off <<= 1) {
    int t = (tid >= off) ? sm[tid - off] : 0;
    __syncthreads();
    sm[tid] += t;
    __syncthreads();
  }
  if (i < N) incl[i] = sm[tid];
  if (tid == 1023) bsum[blockIdx.x] = sm[1023];
}

// ---------------- scan of block sums (nb <= 128) ----------------
__global__ void k_scan2(const int* __restrict__ bsum, int nb, int* __restrict__ boff) {
  __shared__ int sm[128];
  int tid = threadIdx.x;
  int v = (tid < nb) ? bsum[tid] : 0;
  sm[tid] = v;
  __syncthreads();
  for (int off = 1; off < 128; off <<= 1) {
    int t = (tid >= off) ? sm[tid - off] : 0;
    __syncthreads();
    sm[tid] += t;
    __syncthreads();
  }
  if (tid < nb) boff[tid] = sm[tid] - v;  // exclusive
}

// ---------------- row_ptr / cursor / dinv ----------------
__global__ void k_aux(const int* __restrict__ cnt, const int* __restrict__ incl,
                      const int* __restrict__ boff, int N, int E,
                      int* __restrict__ row_ptr, int* __restrict__ cursor,
                      float* __restrict__ dinv) {
  int i = blockIdx.x * blockDim.x + threadIdx.x;
  if (i < N) {
    int rp = incl[i] - cnt[i] + boff[i >> 10];
    row_ptr[i] = rp;
    cursor[i] = rp;
    dinv[i] = 1.0f / sqrtf((float)(cnt[i] + 1));  // +1 self-loop
  } else if (i == N) {
    row_ptr[N] = E;
  }
}

// ---------------- weight prep: W[k][n] fp32 -> lane-ordered bf16 hi/lo fragments -----
__global__ void k_prepw(const float* __restrict__ W1, const float* __restrict__ W2,
                        const float* __restrict__ W3,
                        unsigned short* __restrict__ w1h, unsigned short* __restrict__ w1l,
                        unsigned short* __restrict__ w2h, unsigned short* __restrict__ w2l,
                        unsigned short* __restrict__ w3h, unsigned short* __restrict__ w3l) {
  const int K = 128;
  int idx = blockIdx.x * 256 + threadIdx.x;
  const float* W;
  unsigned short *oh, *ol;
  int Nn, base;
  if (idx < 16384) { W = W1; Nn = 128; oh = w1h; ol = w1l; base = idx; }
  else if (idx < 32768) { W = W2; Nn = 128; oh = w2h; ol = w2l; base = idx - 16384; }
  else if (idx < 40960) { W = W3; Nn = 64; oh = w3h; ol = w3l; base = idx - 32768; }
  else return;
  int n = base / K, k = base % K;
  float w = W[(size_t)k * Nn + n];
  unsigned short h = f2bf(w);
  unsigned short l = f2bf(w - bf2f(h));
  int nf = n >> 4, mloc = n & 15, kci = k >> 5, quad = (k >> 3) & 3, j = k & 7;
  size_t o = ((size_t)((nf * 4 + kci) * 64 + quad * 16 + mloc)) * 8 + j;
  oh[o] = h;
  ol[o] = l;
}

// ---------------- GEMM device body (shared by fused + standalone kernels) ------------
template <int NFW>
static __device__ __forceinline__ void gemm_body(const float* __restrict__ A,
                                                 const unsigned short* __restrict__ Wfh,
                                                 const unsigned short* __restrict__ Wfl,
                                                 const float* __restrict__ dinv,
                                                 unsigned short* __restrict__ P, int M,
                                                 int blk) {
  const int K = 128;
  __shared__ unsigned short Ah[64][136];
  __shared__ unsigned short Al[64][136];
  int tid = threadIdx.x;
  int m0 = blk * 64;
  int w = tid >> 6, lane = tid & 63;

  bf16x8 bh[NFW][4], bl[NFW][4];
#pragma unroll
  for (int i = 0; i < NFW; ++i)
#pragma unroll
    for (int kci = 0; kci < 4; ++kci) {
      size_t o = ((size_t)(((w * NFW + i) * 4 + kci) * 64 + lane)) * 8;
      bh[i][kci] = *(const bf16x8*)&Wfh[o];
      bl[i][kci] = *(const bf16x8*)&Wfl[o];
    }

#pragma unroll
  for (int q = 0; q < 8; ++q) {
    int f = q * 256 + tid;
    int m = f >> 5, k4 = f & 31;
    int row = m0 + m;
    if (row >= M) row = M - 1;
    float4 v = *(const float4*)&A[(size_t)row * K + k4 * 4];
    unsigned short h0 = f2bf(v.x), h1 = f2bf(v.y), h2 = f2bf(v.z), h3 = f2bf(v.w);
    unsigned short l0 = f2bf(v.x - bf2f(h0)), l1 = f2bf(v.y - bf2f(h1));
    unsigned short l2 = f2bf(v.z - bf2f(h2)), l3 = f2bf(v.w - bf2f(h3));
    uint2 hh, ll;
    hh.x = (unsigned)h0 | ((unsigned)h1 << 16);
    hh.y = (unsigned)h2 | ((unsigned)h3 << 16);
    ll.x = (unsigned)l0 | ((unsigned)l1 << 16);
    ll.y = (unsigned)l2 | ((unsigned)l3 << 16);
    *(uint2*)&Ah[m][k4 * 4] = hh;
    *(uint2*)&Al[m][k4 * 4] = ll;
  }
  __syncthreads();

  int mloc = lane & 15, quad = lane >> 4;
  f32x4 acc[4][NFW];
#pragma unroll
  for (int rt = 0; rt < 4; ++rt)
#pragma unroll
    for (int i = 0; i < NFW; ++i) acc[rt][i] = (f32x4){0.f, 0.f, 0.f, 0.f};

#pragma unroll
  for (int rt = 0; rt < 4; ++rt) {
    const unsigned short* ph = &Ah[rt * 16 + mloc][quad * 8];
    const unsigned short* pl = &Al[rt * 16 + mloc][quad * 8];
#pragma unroll
    for (int kci = 0; kci < 4; ++kci) {
      bf16x8 ah = *(const bf16x8*)(ph + kci * 32);
      bf16x8 al = *(const bf16x8*)(pl + kci * 32);
#pragma unroll
      for (int i = 0; i < NFW; ++i) {
        acc[rt][i] = __builtin_amdgcn_mfma_f32_16x16x32_bf16(al, bh[i][kci], acc[rt][i], 0, 0, 0);
        acc[rt][i] = __builtin_amdgcn_mfma_f32_16x16x32_bf16(ah, bl[i][kci], acc[rt][i], 0, 0, 0);
        acc[rt][i] = __builtin_amdgcn_mfma_f32_16x16x32_bf16(ah, bh[i][kci], acc[rt][i], 0, 0, 0);
      }
    }
  }

#pragma unroll
  for (int rt = 0; rt < 4; ++rt) {
    int rbase = m0 + rt * 16 + quad * 4;
#pragma unroll
    for (int r = 0; r < 4; ++r) {
      int row = rbase + r;
      if (row < M) {
        float dv = dinv[row];
#pragma unroll
        for (int i = 0; i < NFW; ++i) {
          int nf = w * NFW + i;
          size_t o = (size_t)(nf >> 1) * M * 32 + (size_t)row * 32 + ((nf & 1) * 16 + mloc);
          P[o] = f2bf(acc[rt][i][r] * dv);
        }
      }
    }
  }
}

// ---------------- standalone MFMA GEMM (layers 2,3) ----------------
template <int NFW>
__global__ __launch_bounds__(256) void k_gemm_mfma(const float* __restrict__ A,
                                                   const unsigned short* __restrict__ Wfh,
                                                   const unsigned short* __restrict__ Wfl,
                                                   const float* __restrict__ dinv,
                                                   unsigned short* __restrict__ P, int M) {
  gemm_body<NFW>(A, Wfh, Wfl, dinv, P, M, blockIdx.x);
}

// ---------------- FUSED: layer-1 GEMM (blocks < gx) + CSR fill (rest) ----------------
// fill and gemm1 are independent (both need only k_aux); fill is ~95% idle
// (VALUBusy 5%, HBM 19%), so the gemm rides in its latency shadow.
// Fill's XCD binning uses GLOBAL blockIdx%8; among the 1024 fill blocks each
// residue appears exactly 128x, and (blockIdx-gx)>>3 enumerates 0..127 per
// residue -> full edge coverage, each edge exactly once.
__global__ __launch_bounds__(256) void k_fill_gemm(const float* __restrict__ A,
                                                   const unsigned short* __restrict__ Wfh,
                                                   const unsigned short* __restrict__ Wfl,
                                                   const float* __restrict__ dinv,
                                                   unsigned short* __restrict__ P, int M,
                                                   const int* __restrict__ edge, int E, int N,
                                                   int* __restrict__ cursor, int* __restrict__ srcs,
                                                   int gx) {
  if ((int)blockIdx.x < gx) {
    gemm_body<2>(A, Wfh, Wfl, dinv, P, M, blockIdx.x);
  } else {
    int grp = blockIdx.x & 7;
    int bslot = (blockIdx.x - gx) >> 3;
    int nslot = (gridDim.x - gx) >> 3;
    int lo = (int)(((long long)N * grp) >> 3);
    int hi = (int)(((long long)N * (grp + 1)) >> 3);
    for (int e = bslot * blockDim.x + threadIdx.x; e < E; e += nslot * blockDim.x) {
      int d = edge[E + e];
      if (d >= lo && d < hi) {
        int s = edge[e];
        int pos = atomicAdd(&cursor[d], 1);
        srcs[pos] = s;
      }
    }
  }
}

// ---------------- full-line sliced aggregation, 4-deep gather MLP ----------------
// Slice = 32 ch = 64-B node row; slice served by XCD pair (C=128) / quad (C=64).
// Inner loop issues 4 independent 64-B gathers before accumulating (strictly
// in edge order -> bitwise-identical output).
template <int C, int RELU, int POOL>
__global__ __launch_bounds__(256) void k_agg4(const unsigned short* __restrict__ P,
                                              const int* __restrict__ row_ptr,
                                              const int* __restrict__ srcs,
                                              const float* __restrict__ dinv,
                                              const float* __restrict__ bias,
                                              float* __restrict__ Hout,
                                              unsigned* __restrict__ minenc, int N) {
  const int NS2 = C / 32;
  const int R = 8 / NS2;
  const int CAP = 448;
  __shared__ int s_idx[4][CAP];
  __shared__ float s_red[4][32];
  int tid = threadIdx.x;
  int wv = tid >> 6, lane = tid & 63;
  int b8 = blockIdx.x & 7;
  int slice = b8 / R, part = b8 % R;
  int g0 = ((blockIdx.x >> 3) * R + part) * 64 + wv * 16;
  const char* Pb = (const char*)P + (size_t)slice * N * 64;

  int i = lane >> 2, q = lane & 3;
  unsigned qoff = (unsigned)q * 16u;
  int d = g0 + i;
  int dc = d < N ? d : N - 1;
  bool valid = d < N;

  int e0 = row_ptr[g0 < N ? g0 : N];
  int e1 = row_ptr[(g0 + 16) < N ? (g0 + 16) : N];
  int lo_n = row_ptr[dc];
  int hi_n = row_ptr[valid ? d + 1 : dc];

  float a[8];
  {
    uint4 v = *(const uint4*)(Pb + ((unsigned)dc * 64u + qoff));
    a[0] = __uint_as_float(v.x << 16);
    a[1] = __uint_as_float(v.x & 0xffff0000u);
    a[2] = __uint_as_float(v.y << 16);
    a[3] = __uint_as_float(v.y & 0xffff0000u);
    a[4] = __uint_as_float(v.z << 16);
    a[5] = __uint_as_float(v.z & 0xffff0000u);
    a[6] = __uint_as_float(v.w << 16);
    a[7] = __uint_as_float(v.w & 0xffff0000u);
  }

  for (int w0 = e0; w0 < e1; w0 += CAP) {
    int wend = min(w0 + CAP, e1);
    int cnt = wend - w0;
    __builtin_amdgcn_wave_barrier();
    for (int t = lane; t < cnt; t += 64) s_idx[wv][t] = srcs[w0 + t];
    __builtin_amdgcn_wave_barrier();
    int j = max(lo_n, w0), hi = min(hi_n, wend);
    for (; j + 4 <= hi; j += 4) {
      unsigned i0 = (unsigned)s_idx[wv][j - w0];
      unsigned i1 = (unsigned)s_idx[wv][j - w0 + 1];
      unsigned i2 = (unsigned)s_idx[wv][j - w0 + 2];
      unsigned i3 = (unsigned)s_idx[wv][j - w0 + 3];
      uint4 v0 = *(const uint4*)(Pb + (i0 * 64u + qoff));
      uint4 v1 = *(const uint4*)(Pb + (i1 * 64u + qoff));
      uint4 v2 = *(const uint4*)(Pb + (i2 * 64u + qoff));
      uint4 v3 = *(const uint4*)(Pb + (i3 * 64u + qoff));
      acc8(a, v0);
      acc8(a, v1);
      acc8(a, v2);
      acc8(a, v3);
    }
    for (; j < hi; ++j) {
      unsigned i0 = (unsigned)s_idx[wv][j - w0];
      uint4 v0 = *(const uint4*)(Pb + (i0 * 64u + qoff));
      acc8(a, v0);
    }
  }

  int c0 = slice * 32 + q * 8;
  float dv = dinv[dc];
  float4 bv0 = *(const float4*)&bias[c0];
  float4 bv1 = *(const float4*)&bias[c0 + 4];
  float h[8];
  h[0] = dv * a[0] + bv0.x; h[1] = dv * a[1] + bv0.y;
  h[2] = dv * a[2] + bv0.z; h[3] = dv * a[3] + bv0.w;
  h[4] = dv * a[4] + bv1.x; h[5] = dv * a[5] + bv1.y;
  h[6] = dv * a[6] + bv1.z; h[7] = dv * a[7] + bv1.w;
  if (RELU) {
#pragma unroll
    for (int k = 0; k < 8; ++k) h[k] = fmaxf(h[k], 0.f);
  }

  if (POOL) {
    if (!valid) {
#pragma unroll
      for (int k = 0; k < 8; ++k) h[k] = FLT_MAX;
    }
#pragma unroll
    for (int off = 4; off < 64; off <<= 1) {
#pragma unroll
      for (int k = 0; k < 8; ++k) h[k] = fminf(h[k], __shfl_xor(h[k], off, 64));
    }
    if (lane < 4) {
#pragma unroll
      for (int k = 0; k < 8; ++k) s_red[wv][q * 8 + k] = h[k];
    }
    __syncthreads();
    if (tid < 32) {
      float m = fminf(fminf(s_red[0][tid], s_red[1][tid]),
                      fminf(s_red[2][tid], s_red[3][tid]));
      atomicMin(&minenc[slice * 32 + tid], enc_min(m));
    }
  } else if (valid) {
    float4 o0 = make_float4(h[0], h[1], h[2], h[3]);
    float4 o1 = make_float4(h[4], h[5], h[6], h[7]);
    *(float4*)&Hout[(size_t)d * C + c0] = o0;
    *(float4*)&Hout[(size_t)d * C + c0 + 4] = o1;
  }
}

__global__ void k_decode(const unsigned* __restrict__ minenc, float* __restrict__ out) {
  int c = threadIdx.x;
  unsigned k = minenc[c];
  unsigned u = (k & 0x80000000u) ? (k & 0x7FFFFFFFu) : ~k;
  out[c] = __uint_as_float(u);
}

// ---------------- launch ----------------
extern "C" void kernel_launch(void* const* d_in, const int* in_sizes, int n_in,
                              void* d_out, int out_size, void* d_ws, size_t ws_size,
                              hipStream_t stream) {
  const float* X  = (const float*)d_in[0];
  const int* edge = (const int*)d_in[1];
  const float* W1 = (const float*)d_in[2];
  const float* b1 = (const float*)d_in[3];
  const float* W2 = (const float*)d_in[4];
  const float* b2 = (const float*)d_in[5];
  const float* W3 = (const float*)d_in[6];
  const float* b3 = (const float*)d_in[7];
  float* out = (float*)d_out;

  const int IN_CH = 128;
  int N = in_sizes[0] / IN_CH;
  int E = in_sizes[1] / 2;

  char* ws = (char*)d_ws;
  size_t off = 0;
  auto alloc = [&](size_t bytes) {
    void* p = ws + off;
    off = (off + bytes + 255) & ~(size_t)255;
    return p;
  };
  unsigned short* P = (unsigned short*)alloc((size_t)N * 128 * 2);  // 25.6 MB bf16, sliced
  float* H       = (float*)alloc((size_t)N * 128 * 4);              // 51.2 MB
  int* srcs      = (int*)alloc((size_t)E * 4);                      // 6.4 MB
  int* cnt       = (int*)alloc((size_t)N * 4);
  int* incl      = (int*)alloc((size_t)N * 4);
  int* row_ptr   = (int*)alloc((size_t)(N + 1) * 4);
  int* cursor    = (int*)alloc((size_t)N * 4);
  float* dinv    = (float*)alloc((size_t)N * 4);
  int* bsum      = (int*)alloc(1024);
  int* boff      = (int*)alloc(1024);
  unsigned* minenc = (unsigned*)alloc(256);
  unsigned short* w1h = (unsigned short*)alloc(16384 * 2);
  unsigned short* w1l = (unsigned short*)alloc(16384 * 2);
  unsigned short* w2h = (unsigned short*)alloc(16384 * 2);
  unsigned short* w2l = (unsigned short*)alloc(16384 * 2);
  unsigned short* w3h = (unsigned short*)alloc(8192 * 2);
  unsigned short* w3l = (unsigned short*)alloc(8192 * 2);

  hipMemsetAsync(cnt, 0, (size_t)N * 4, stream);
  hipMemsetAsync(minenc, 0xFF, 64 * 4, stream);  // encoded +max

  int nb = (N + 1023) / 1024;
  int gx = (N + 63) / 64;
  k_prepw<<<160, 256, 0, stream>>>(W1, W2, W3, w1h, w1l, w2h, w2l, w3h, w3l);
  k_count<<<1024, 256, 0, stream>>>(edge, E, N, cnt);
  k_scan1<<<nb, 1024, 0, stream>>>(cnt, N, incl, bsum);
  k_scan2<<<1, 128, 0, stream>>>(bsum, nb, boff);
  k_aux<<<(N + 256) / 256, 256, 0, stream>>>(cnt, incl, boff, N, E, row_ptr, cursor, dinv);

  int c128 = (N + 127) / 128;  // chunks for C=128 (R=2 parts x 64 nodes)
  int c64  = (N + 255) / 256;  // chunks for C=64  (R=4 parts x 64 nodes)
  // layer 1: fused fill + gemm1
  k_fill_gemm<<<gx + 1024, 256, 0, stream>>>(X, w1h, w1l, dinv, P, N,
                                             edge, E, N, cursor, srcs, gx);
  k_agg4<128, 1, 0><<<c128 * 8, 256, 0, stream>>>(P, row_ptr, srcs, dinv, b1, H, minenc, N);
  // layer 2
  k_gemm_mfma<2><<<gx, 256, 0, stream>>>(H, w2h, w2l, dinv, P, N);
  k_agg4<128, 1, 0><<<c128 * 8, 256, 0, stream>>>(P, row_ptr, srcs, dinv, b2, H, minenc, N);
  // layer 3 (64 ch, no relu) with fused min-pool
  k_gemm_mfma<1><<<gx, 256, 0, stream>>>(H, w3h, w3l, dinv, P, N);
  k_agg4<64, 0, 1><<<c64 * 8, 256, 0, stream>>>(P, row_ptr, srcs, dinv, b3, nullptr, minenc, N);
  // decode encoded mins -> out[64]
  k_decode<<<1, 64, 0, stream>>>(minenc, out);
}

// Round 12
// 476.886 us; speedup vs baseline: 1.2300x; 1.0080x over previous
//
#include <hip/hip_runtime.h>
#include <stdint.h>
#include <stddef.h>
#include <float.h>

typedef short bf16x8 __attribute__((ext_vector_type(8)));
typedef float f32x4 __attribute__((ext_vector_type(4)));

// ---------------- helpers ----------------
static __device__ __forceinline__ unsigned enc_min(float v) {
  unsigned u = __float_as_uint(v);
  return (u & 0x80000000u) ? ~u : (u | 0x80000000u);
}
static __device__ __forceinline__ unsigned short f2bf(float f) {
  unsigned u = __float_as_uint(f);
  u += 0x7fffu + ((u >> 16) & 1u);
  return (unsigned short)(u >> 16);
}
static __device__ __forceinline__ float bf2f(unsigned short b) {
  return __uint_as_float(((unsigned)b) << 16);
}
static __device__ __forceinline__ void acc8(float* a, uint4 v) {
  a[0] += __uint_as_float(v.x << 16);
  a[1] += __uint_as_float(v.x & 0xffff0000u);
  a[2] += __uint_as_float(v.y << 16);
  a[3] += __uint_as_float(v.y & 0xffff0000u);
  a[4] += __uint_as_float(v.z << 16);
  a[5] += __uint_as_float(v.z & 0xffff0000u);
  a[6] += __uint_as_float(v.w << 16);
  a[7] += __uint_as_float(v.w & 0xffff0000u);
}

// ---------------- privatized degree count: ONE pass over edges ----------------
// Each block increments its own XCD's private copy (blockIdx%8 -> XCD
// heuristic): atomics stay L2-local, edge dst array is read ONCE (6.4 MB)
// instead of 8x (51 MB, the old XCD-binned scheme). Counts are commutative,
// so privatize+reduce replaces binning. Reduce folds into k_scan1.
__global__ void k_count8(const int* __restrict__ edge, int E, int N,
                         int* __restrict__ cnt8) {
  int* cnt = cnt8 + (size_t)(blockIdx.x & 7) * N;
  int stride = gridDim.x * blockDim.x;
  for (int e = blockIdx.x * blockDim.x + threadIdx.x; e < E; e += stride) {
    atomicAdd(&cnt[edge[E + e]], 1);
  }
}

// ---------------- block inclusive scan (1024/block) + 8-way cnt reduce ----------------
__global__ void k_scan1(const int* __restrict__ cnt8, int N,
                        int* __restrict__ cnt, int* __restrict__ incl,
                        int* __restrict__ bsum) {
  __shared__ int sm[1024];
  int tid = threadIdx.x;
  int i = blockIdx.x * 1024 + tid;
  int v = 0;
  if (i < N) {
#pragma unroll
    for (int g = 0; g < 8; ++g) v += cnt8[(size_t)g * N + i];
    cnt[i] = v;  // summed degree for k_aux
  }
  sm[tid] = v;
  __syncthreads();
  for (int off = 1; off < 1024; off <<= 1) {
    int t = (tid >= off) ? sm[tid - off] : 0;
    __syncthreads();
    sm[tid] += t;
    __syncthreads();
  }
  if (i < N) incl[i] = sm[tid];
  if (tid == 1023) bsum[blockIdx.x] = sm[1023];
}

// ---------------- scan of block sums (nb <= 128) ----------------
__global__ void k_scan2(const int* __restrict__ bsum, int nb, int* __restrict__ boff) {
  __shared__ int sm[128];
  int tid = threadIdx.x;
  int v = (tid < nb) ? bsum[tid] : 0;
  sm[tid] = v;
  __syncthreads();
  for (int off = 1; off < 128; off <<= 1) {
    int t = (tid >= off) ? sm[tid - off] : 0;
    __syncthreads();
    sm[tid] += t;
    __syncthreads();
  }
  if (tid < nb) boff[tid] = sm[tid] - v;  // exclusive
}

// ---------------- row_ptr / cursor / dinv ----------------
__global__ void k_aux(const int* __restrict__ cnt, const int* __restrict__ incl,
                      const int* __restrict__ boff, int N, int E,
                      int* __restrict__ row_ptr, int* __restrict__ cursor,
                      float* __restrict__ dinv) {
  int i = blockIdx.x * blockDim.x + threadIdx.x;
  if (i < N) {
    int rp = incl[i] - cnt[i] + boff[i >> 10];
    row_ptr[i] = rp;
    cursor[i] = rp;
    dinv[i] = 1.0f / sqrtf((float)(cnt[i] + 1));  // +1 self-loop
  } else if (i == N) {
    row_ptr[N] = E;
  }
}

// ---------------- weight prep: W[k][n] fp32 -> lane-ordered bf16 hi/lo fragments -----
__global__ void k_prepw(const float* __restrict__ W1, const float* __restrict__ W2,
                        const float* __restrict__ W3,
                        unsigned short* __restrict__ w1h, unsigned short* __restrict__ w1l,
                        unsigned short* __restrict__ w2h, unsigned short* __restrict__ w2l,
                        unsigned short* __restrict__ w3h, unsigned short* __restrict__ w3l) {
  const int K = 128;
  int idx = blockIdx.x * 256 + threadIdx.x;
  const float* W;
  unsigned short *oh, *ol;
  int Nn, base;
  if (idx < 16384) { W = W1; Nn = 128; oh = w1h; ol = w1l; base = idx; }
  else if (idx < 32768) { W = W2; Nn = 128; oh = w2h; ol = w2l; base = idx - 16384; }
  else if (idx < 40960) { W = W3; Nn = 64; oh = w3h; ol = w3l; base = idx - 32768; }
  else return;
  int n = base / K, k = base % K;
  float w = W[(size_t)k * Nn + n];
  unsigned short h = f2bf(w);
  unsigned short l = f2bf(w - bf2f(h));
  int nf = n >> 4, mloc = n & 15, kci = k >> 5, quad = (k >> 3) & 3, j = k & 7;
  size_t o = ((size_t)((nf * 4 + kci) * 64 + quad * 16 + mloc)) * 8 + j;
  oh[o] = h;
  ol[o] = l;
}

// ---------------- GEMM device body (shared by fused + standalone kernels) ------------
template <int NFW>
static __device__ __forceinline__ void gemm_body(const float* __restrict__ A,
                                                 const unsigned short* __restrict__ Wfh,
                                                 const unsigned short* __restrict__ Wfl,
                                                 const float* __restrict__ dinv,
                                                 unsigned short* __restrict__ P, int M,
                                                 int blk) {
  const int K = 128;
  __shared__ unsigned short Ah[64][136];
  __shared__ unsigned short Al[64][136];
  int tid = threadIdx.x;
  int m0 = blk * 64;
  int w = tid >> 6, lane = tid & 63;

  bf16x8 bh[NFW][4], bl[NFW][4];
#pragma unroll
  for (int i = 0; i < NFW; ++i)
#pragma unroll
    for (int kci = 0; kci < 4; ++kci) {
      size_t o = ((size_t)(((w * NFW + i) * 4 + kci) * 64 + lane)) * 8;
      bh[i][kci] = *(const bf16x8*)&Wfh[o];
      bl[i][kci] = *(const bf16x8*)&Wfl[o];
    }

#pragma unroll
  for (int q = 0; q < 8; ++q) {
    int f = q * 256 + tid;
    int m = f >> 5, k4 = f & 31;
    int row = m0 + m;
    if (row >= M) row = M - 1;
    float4 v = *(const float4*)&A[(size_t)row * K + k4 * 4];
    unsigned short h0 = f2bf(v.x), h1 = f2bf(v.y), h2 = f2bf(v.z), h3 = f2bf(v.w);
    unsigned short l0 = f2bf(v.x - bf2f(h0)), l1 = f2bf(v.y - bf2f(h1));
    unsigned short l2 = f2bf(v.z - bf2f(h2)), l3 = f2bf(v.w - bf2f(h3));
    uint2 hh, ll;
    hh.x = (unsigned)h0 | ((unsigned)h1 << 16);
    hh.y = (unsigned)h2 | ((unsigned)h3 << 16);
    ll.x = (unsigned)l0 | ((unsigned)l1 << 16);
    ll.y = (unsigned)l2 | ((unsigned)l3 << 16);
    *(uint2*)&Ah[m][k4 * 4] = hh;
    *(uint2*)&Al[m][k4 * 4] = ll;
  }
  __syncthreads();

  int mloc = lane & 15, quad = lane >> 4;
  f32x4 acc[4][NFW];
#pragma unroll
  for (int rt = 0; rt < 4; ++rt)
#pragma unroll
    for (int i = 0; i < NFW; ++i) acc[rt][i] = (f32x4){0.f, 0.f, 0.f, 0.f};

#pragma unroll
  for (int rt = 0; rt < 4; ++rt) {
    const unsigned short* ph = &Ah[rt * 16 + mloc][quad * 8];
    const unsigned short* pl = &Al[rt * 16 + mloc][quad * 8];
#pragma unroll
    for (int kci = 0; kci < 4; ++kci) {
      bf16x8 ah = *(const bf16x8*)(ph + kci * 32);
      bf16x8 al = *(const bf16x8*)(pl + kci * 32);
#pragma unroll
      for (int i = 0; i < NFW; ++i) {
        acc[rt][i] = __builtin_amdgcn_mfma_f32_16x16x32_bf16(al, bh[i][kci], acc[rt][i], 0, 0, 0);
        acc[rt][i] = __builtin_amdgcn_mfma_f32_16x16x32_bf16(ah, bl[i][kci], acc[rt][i], 0, 0, 0);
        acc[rt][i] = __builtin_amdgcn_mfma_f32_16x16x32_bf16(ah, bh[i][kci], acc[rt][i], 0, 0, 0);
      }
    }
  }

#pragma unroll
  for (int rt = 0; rt < 4; ++rt) {
    int rbase = m0 + rt * 16 + quad * 4;
#pragma unroll
    for (int r = 0; r < 4; ++r) {
      int row = rbase + r;
      if (row < M) {
        float dv = dinv[row];
#pragma unroll
        for (int i = 0; i < NFW; ++i) {
          int nf = w * NFW + i;
          size_t o = (size_t)(nf >> 1) * M * 32 + (size_t)row * 32 + ((nf & 1) * 16 + mloc);
          P[o] = f2bf(acc[rt][i][r] * dv);
        }
      }
    }
  }
}

// ---------------- standalone MFMA GEMM (layers 2,3) ----------------
template <int NFW>
__global__ __launch_bounds__(256) void k_gemm_mfma(const float* __restrict__ A,
                                                   const unsigned short* __restrict__ Wfh,
                                                   const unsigned short* __restrict__ Wfl,
                                                   const float* __restrict__ dinv,
                                                   unsigned short* __restrict__ P, int M) {
  gemm_body<NFW>(A, Wfh, Wfl, dinv, P, M, blockIdx.x);
}

// ---------------- FUSED: layer-1 GEMM (blocks < gx) + CSR fill (rest) ----------------
// fill is ~95% idle, gemm1 rides in its latency shadow (net win R11: -10 us).
__global__ __launch_bounds__(256) void k_fill_gemm(const float* __restrict__ A,
                                                   const unsigned short* __restrict__ Wfh,
                                                   const unsigned short* __restrict__ Wfl,
                                                   const float* __restrict__ dinv,
                                                   unsigned short* __restrict__ P, int M,
                                                   const int* __restrict__ edge, int E, int N,
                                                   int* __restrict__ cursor, int* __restrict__ srcs,
                                                   int gx) {
  if ((int)blockIdx.x < gx) {
    gemm_body<2>(A, Wfh, Wfl, dinv, P, M, blockIdx.x);
  } else {
    int grp = blockIdx.x & 7;
    int bslot = (blockIdx.x - gx) >> 3;
    int nslot = (gridDim.x - gx) >> 3;
    int lo = (int)(((long long)N * grp) >> 3);
    int hi = (int)(((long long)N * (grp + 1)) >> 3);
    for (int e = bslot * blockDim.x + threadIdx.x; e < E; e += nslot * blockDim.x) {
      int d = edge[E + e];
      if (d >= lo && d < hi) {
        int s = edge[e];
        int pos = atomicAdd(&cursor[d], 1);
        srcs[pos] = s;
      }
    }
  }
}

// ---------------- full-line sliced aggregation, 4-deep gather MLP ----------------
template <int C, int RELU, int POOL>
__global__ __launch_bounds__(256) void k_agg4(const unsigned short* __restrict__ P,
                                              const int* __restrict__ row_ptr,
                                              const int* __restrict__ srcs,
                                              const float* __restrict__ dinv,
                                              const float* __restrict__ bias,
                                              float* __restrict__ Hout,
                                              unsigned* __restrict__ minenc, int N) {
  const int NS2 = C / 32;
  const int R = 8 / NS2;
  const int CAP = 448;
  __shared__ int s_idx[4][CAP];
  __shared__ float s_red[4][32];
  int tid = threadIdx.x;
  int wv = tid >> 6, lane = tid & 63;
  int b8 = blockIdx.x & 7;
  int slice = b8 / R, part = b8 % R;
  int g0 = ((blockIdx.x >> 3) * R + part) * 64 + wv * 16;
  const char* Pb = (const char*)P + (size_t)slice * N * 64;

  int i = lane >> 2, q = lane & 3;
  unsigned qoff = (unsigned)q * 16u;
  int d = g0 + i;
  int dc = d < N ? d : N - 1;
  bool valid = d < N;

  int e0 = row_ptr[g0 < N ? g0 : N];
  int e1 = row_ptr[(g0 + 16) < N ? (g0 + 16) : N];
  int lo_n = row_ptr[dc];
  int hi_n = row_ptr[valid ? d + 1 : dc];

  float a[8];
  {
    uint4 v = *(const uint4*)(Pb + ((unsigned)dc * 64u + qoff));
    a[0] = __uint_as_float(v.x << 16);
    a[1] = __uint_as_float(v.x & 0xffff0000u);
    a[2] = __uint_as_float(v.y << 16);
    a[3] = __uint_as_float(v.y & 0xffff0000u);
    a[4] = __uint_as_float(v.z << 16);
    a[5] = __uint_as_float(v.z & 0xffff0000u);
    a[6] = __uint_as_float(v.w << 16);
    a[7] = __uint_as_float(v.w & 0xffff0000u);
  }

  for (int w0 = e0; w0 < e1; w0 += CAP) {
    int wend = min(w0 + CAP, e1);
    int cnt = wend - w0;
    __builtin_amdgcn_wave_barrier();
    for (int t = lane; t < cnt; t += 64) s_idx[wv][t] = srcs[w0 + t];
    __builtin_amdgcn_wave_barrier();
    int j = max(lo_n, w0), hi = min(hi_n, wend);
    for (; j + 4 <= hi; j += 4) {
      unsigned i0 = (unsigned)s_idx[wv][j - w0];
      unsigned i1 = (unsigned)s_idx[wv][j - w0 + 1];
      unsigned i2 = (unsigned)s_idx[wv][j - w0 + 2];
      unsigned i3 = (unsigned)s_idx[wv][j - w0 + 3];
      uint4 v0 = *(const uint4*)(Pb + (i0 * 64u + qoff));
      uint4 v1 = *(const uint4*)(Pb + (i1 * 64u + qoff));
      uint4 v2 = *(const uint4*)(Pb + (i2 * 64u + qoff));
      uint4 v3 = *(const uint4*)(Pb + (i3 * 64u + qoff));
      acc8(a, v0);
      acc8(a, v1);
      acc8(a, v2);
      acc8(a, v3);
    }
    for (; j < hi; ++j) {
      unsigned i0 = (unsigned)s_idx[wv][j - w0];
      uint4 v0 = *(const uint4*)(Pb + (i0 * 64u + qoff));
      acc8(a, v0);
    }
  }

  int c0 = slice * 32 + q * 8;
  float dv = dinv[dc];
  float4 bv0 = *(const float4*)&bias[c0];
  float4 bv1 = *(const float4*)&bias[c0 + 4];
  float h[8];
  h[0] = dv * a[0] + bv0.x; h[1] = dv * a[1] + bv0.y;
  h[2] = dv * a[2] + bv0.z; h[3] = dv * a[3] + bv0.w;
  h[4] = dv * a[4] + bv1.x; h[5] = dv * a[5] + bv1.y;
  h[6] = dv * a[6] + bv1.z; h[7] = dv * a[7] + bv1.w;
  if (RELU) {
#pragma unroll
    for (int k = 0; k < 8; ++k) h[k] = fmaxf(h[k], 0.f);
  }

  if (POOL) {
    if (!valid) {
#pragma unroll
      for (int k = 0; k < 8; ++k) h[k] = FLT_MAX;
    }
#pragma unroll
    for (int off = 4; off < 64; off <<= 1) {
#pragma unroll
      for (int k = 0; k < 8; ++k) h[k] = fminf(h[k], __shfl_xor(h[k], off, 64));
    }
    if (lane < 4) {
#pragma unroll
      for (int k = 0; k < 8; ++k) s_red[wv][q * 8 + k] = h[k];
    }
    __syncthreads();
    if (tid < 32) {
      float m = fminf(fminf(s_red[0][tid], s_red[1][tid]),
                      fminf(s_red[2][tid], s_red[3][tid]));
      atomicMin(&minenc[slice * 32 + tid], enc_min(m));
    }
  } else if (valid) {
    float4 o0 = make_float4(h[0], h[1], h[2], h[3]);
    float4 o1 = make_float4(h[4], h[5], h[6], h[7]);
    *(float4*)&Hout[(size_t)d * C + c0] = o0;
    *(float4*)&Hout[(size_t)d * C + c0 + 4] = o1;
  }
}

__global__ void k_decode(const unsigned* __restrict__ minenc, float* __restrict__ out) {
  int c = threadIdx.x;
  unsigned k = minenc[c];
  unsigned u = (k & 0x80000000u) ? (k & 0x7FFFFFFFu) : ~k;
  out[c] = __uint_as_float(u);
}

// ---------------- launch ----------------
extern "C" void kernel_launch(void* const* d_in, const int* in_sizes, int n_in,
                              void* d_out, int out_size, void* d_ws, size_t ws_size,
                              hipStream_t stream) {
  const float* X  = (const float*)d_in[0];
  const int* edge = (const int*)d_in[1];
  const float* W1 = (const float*)d_in[2];
  const float* b1 = (const float*)d_in[3];
  const float* W2 = (const float*)d_in[4];
  const float* b2 = (const float*)d_in[5];
  const float* W3 = (const float*)d_in[6];
  const float* b3 = (const float*)d_in[7];
  float* out = (float*)d_out;

  const int IN_CH = 128;
  int N = in_sizes[0] / IN_CH;
  int E = in_sizes[1] / 2;

  char* ws = (char*)d_ws;
  size_t off = 0;
  auto alloc = [&](size_t bytes) {
    void* p = ws + off;
    off = (off + bytes + 255) & ~(size_t)255;
    return p;
  };
  unsigned short* P = (unsigned short*)alloc((size_t)N * 128 * 2);  // 25.6 MB bf16, sliced
  float* H       = (float*)alloc((size_t)N * 128 * 4);              // 51.2 MB
  int* srcs      = (int*)alloc((size_t)E * 4);                      // 6.4 MB
  int* cnt8      = (int*)alloc((size_t)8 * N * 4);                  // 3.2 MB private copies
  int* cnt       = (int*)alloc((size_t)N * 4);
  int* incl      = (int*)alloc((size_t)N * 4);
  int* row_ptr   = (int*)alloc((size_t)(N + 1) * 4);
  int* cursor    = (int*)alloc((size_t)N * 4);
  float* dinv    = (float*)alloc((size_t)N * 4);
  int* bsum      = (int*)alloc(1024);
  int* boff      = (int*)alloc(1024);
  unsigned* minenc = (unsigned*)alloc(256);
  unsigned short* w1h = (unsigned short*)alloc(16384 * 2);
  unsigned short* w1l = (unsigned short*)alloc(16384 * 2);
  unsigned short* w2h = (unsigned short*)alloc(16384 * 2);
  unsigned short* w2l = (unsigned short*)alloc(16384 * 2);
  unsigned short* w3h = (unsigned short*)alloc(8192 * 2);
  unsigned short* w3l = (unsigned short*)alloc(8192 * 2);

  hipMemsetAsync(cnt8, 0, (size_t)8 * N * 4, stream);
  hipMemsetAsync(minenc, 0xFF, 64 * 4, stream);  // encoded +max

  int nb = (N + 1023) / 1024;
  int gx = (N + 63) / 64;
  k_prepw<<<160, 256, 0, stream>>>(W1, W2, W3, w1h, w1l, w2h, w2l, w3h, w3l);
  k_count8<<<1024, 256, 0, stream>>>(edge, E, N, cnt8);
  k_scan1<<<nb, 1024, 0, stream>>>(cnt8, N, cnt, incl, bsum);
  k_scan2<<<1, 128, 0, stream>>>(bsum, nb, boff);
  k_aux<<<(N + 256) / 256, 256, 0, stream>>>(cnt, incl, boff, N, E, row_ptr, cursor, dinv);

  int c128 = (N + 127) / 128;  // chunks for C=128 (R=2 parts x 64 nodes)
  int c64  = (N + 255) / 256;  // chunks for C=64  (R=4 parts x 64 nodes)
  // layer 1: fused fill + gemm1
  k_fill_gemm<<<gx + 1024, 256, 0, stream>>>(X, w1h, w1l, dinv, P, N,
                                             edge, E, N, cursor, srcs, gx);
  k_agg4<128, 1, 0><<<c128 * 8, 256, 0, stream>>>(P, row_ptr, srcs, dinv, b1, H, minenc, N);
  // layer 2
  k_gemm_mfma<2><<<gx, 256, 0, stream>>>(H, w2h, w2l, dinv, P, N);
  k_agg4<128, 1, 0><<<c128 * 8, 256, 0, stream>>>(P, row_ptr, srcs, dinv, b2, H, minenc, N);
  // layer 3 (64 ch, no relu) with fused min-pool
  k_gemm_mfma<1><<<gx, 256, 0, stream>>>(H, w3h, w3l, dinv, P, N);
  k_agg4<64, 0, 1><<<c64 * 8, 256, 0, stream>>>(P, row_ptr, srcs, dinv, b3, nullptr, minenc, N);
  // decode encoded mins -> out[64]
  k_decode<<<1, 64, 0, stream>>>(minenc, out);
}